// Round 1
// baseline (8501.234 us; speedup 1.0000x reference)
//
#include <hip/hip_runtime.h>

// Problem constants
#define BB 16
#define TT 4096
#define DD 256     // DIM
#define HH 128     // hidden
#define G3 384     // 3*H
#define MM (BB*TT) // 65536 rows

typedef unsigned short u16;
typedef unsigned int u32;
typedef __attribute__((ext_vector_type(8))) short short8;  // 8 bf16 (4 VGPRs)
typedef __attribute__((ext_vector_type(4))) float f32x4;

__device__ __forceinline__ float bf2f(u16 u) {
    return __uint_as_float(((u32)u) << 16);
}
__device__ __forceinline__ u16 f2bf(float f) {
    u32 u = __float_as_uint(f);
    u32 lsb = (u >> 16) & 1u;
    u += 0x7fffu + lsb;      // RNE
    return (u16)(u >> 16);
}

// ---------------- Input-projection GEMM (fp32) ----------------
// XG[dir][m][0:384] = X[m][0:256] @ Wi[dir][0:256][0:384]
#define Bb 128
#define Bn 128
#define Bk 16

__global__ __launch_bounds__(256) void gemm_in(const float* __restrict__ X,
                                               const float* __restrict__ Wi,
                                               float* __restrict__ XG) {
    __shared__ __align__(16) float As[Bk][Bb + 4];
    __shared__ __align__(16) float Bs[Bk][Bn + 4];
    const int tid = threadIdx.x;
    const int m0  = blockIdx.y * Bb;
    const int nb  = blockIdx.x;
    const int n0  = nb * Bn;
    const int dir = (n0 >= G3) ? 1 : 0;
    const int nloc0 = n0 - dir * G3;
    const float* Wd = Wi + (size_t)dir * DD * G3;

    const int tx = tid & 15;
    const int ty = tid >> 4;
    float acc[8][8];
    #pragma unroll
    for (int i = 0; i < 8; ++i)
        #pragma unroll
        for (int j = 0; j < 8; ++j) acc[i][j] = 0.f;

    for (int k0 = 0; k0 < DD; k0 += Bk) {
        #pragma unroll
        for (int p = 0; p < 2; ++p) {
            int idx = tid + p * 256;
            int row = idx >> 2;
            int c4  = (idx & 3) * 4;
            float4 v = *(const float4*)(X + (size_t)(m0 + row) * DD + k0 + c4);
            As[c4 + 0][row] = v.x;
            As[c4 + 1][row] = v.y;
            As[c4 + 2][row] = v.z;
            As[c4 + 3][row] = v.w;
        }
        #pragma unroll
        for (int p = 0; p < 2; ++p) {
            int idx  = tid + p * 256;
            int krow = idx >> 5;
            int c4   = (idx & 31) * 4;
            float4 v = *(const float4*)(Wd + (size_t)(k0 + krow) * G3 + nloc0 + c4);
            *(float4*)(&Bs[krow][c4]) = v;
        }
        __syncthreads();
        #pragma unroll
        for (int k = 0; k < Bk; ++k) {
            float4 a0 = *(const float4*)(&As[k][ty * 8]);
            float4 a1 = *(const float4*)(&As[k][ty * 8 + 4]);
            float4 b0 = *(const float4*)(&Bs[k][tx * 8]);
            float4 b1 = *(const float4*)(&Bs[k][tx * 8 + 4]);
            float av[8] = {a0.x, a0.y, a0.z, a0.w, a1.x, a1.y, a1.z, a1.w};
            float bv[8] = {b0.x, b0.y, b0.z, b0.w, b1.x, b1.y, b1.z, b1.w};
            #pragma unroll
            for (int i = 0; i < 8; ++i)
                #pragma unroll
                for (int j = 0; j < 8; ++j) acc[i][j] += av[i] * bv[j];
        }
        __syncthreads();
    }
    #pragma unroll
    for (int i = 0; i < 8; ++i) {
        int m = m0 + ty * 8 + i;
        float* dst = XG + ((size_t)dir * MM + m) * G3 + nloc0 + tx * 8;
        *(float4*)dst       = make_float4(acc[i][0], acc[i][1], acc[i][2], acc[i][3]);
        *(float4*)(dst + 4) = make_float4(acc[i][4], acc[i][5], acc[i][6], acc[i][7]);
    }
}

// ---------------- MFMA recurrence, one WG per (dir,batch) ----------------
__device__ __forceinline__ float fast_sigmoid(float x) {
    float e = __expf(-x);
    return __builtin_amdgcn_rcpf(1.f + e);
}
__device__ __forceinline__ float fast_tanh(float x) {
    float e = __expf(2.f * x);
    return 1.f - 2.f * __builtin_amdgcn_rcpf(1.f + e);
}

// hi/lo recombine across the lane<32 / lane>=32 split WITHOUT the DS pipe.
// v_permlane32_swap with A=B=g: under any of the documented row-swap
// semantics, A'+B' = g[lane] + g[lane^32] in every lane.
__device__ __forceinline__ float permswap_add(float g) {
    float a = g;
    float b = g;
    asm("v_permlane32_swap_b32 %0, %1" : "+v"(a), "+v"(b));
    return a + b;
}

// xg registers for one substep: 2 col-tiles x 3 gates.
struct XG6 { float r[2], z[2], n[2]; };
__device__ __forceinline__ XG6 load6(const float* p) {
    XG6 v;
    v.r[0] = p[0];   v.r[1] = p[16];
    v.z[0] = p[128]; v.z[1] = p[144];
    v.n[0] = p[256]; v.n[1] = p[272];
    return v;
}

// grid = 32 (dir,batch); block = 256 (4 waves, 1/SIMD). Wave w owns h-cols
// [32w,32w+32) = 2 col-tiles x 3 gates = 6 MFMA tiles (24 MFMAs/wave/step).
// vs round 6 (8 waves): same MFMA-pipe time (24/SIMD = floor) but HALF the
// ds_read_b128 traffic (16 vs 32/step), no ds_bpermute (permlane32_swap on
// VALU instead), 4-wave barrier, half the per-SIMD VALU issue pressure.
//
// Row-split hi/lo trick unchanged: A rows 0-7 carry h_hi, rows 8-15 h_lo;
// one MFMA chain per tile yields hi@W (quads 0-1) and lo@W (quads 2-3);
// permlane32_swap+add recombines to ~fp32 precision.
//
// xg prefetch: depth-4, IN-PLACE reload via 4x unroll (no ring-register
// copies -> no same-iteration vmcnt wait; the load issued at step t is
// first waited on at step t+4, ~4 step-latencies later).
__global__ __launch_bounds__(256, 1) void gru_rec(const float* __restrict__ XG,
                                                  const float* __restrict__ Wh,
                                                  const float* __restrict__ bh,
                                                  float* __restrict__ Xout) {
    const int wg   = blockIdx.x;     // 0..31
    const int dir  = wg & 1;
    const int b    = wg >> 1;
    const int tid  = threadIdx.x;
    const int lane = tid & 63;
    const int wave = tid >> 6;       // 0..3
    const int q    = lane >> 4;      // 0..3
    const int c    = lane & 15;
    const int col0 = wave * 32 + c;  // tile0 column; tile1 = col0+16

    __shared__ __align__(16) u16 hhi[2][HH];   // ping-pong, bf16 hi
    __shared__ __align__(16) u16 hlo[2][HH];   // bf16 lo (residual)

    // ---- B-frag preload (Wh), plain bf16 ----
    // B layout (16x16x32): n = lane&15, k = (lane>>4)*8 + j
    short8 bfr[3][2][4];             // [gate][tile][k-chunk]
    {
        const float* W = Wh + (size_t)dir * HH * G3;
        #pragma unroll
        for (int g = 0; g < 3; ++g)
            #pragma unroll
            for (int ti = 0; ti < 2; ++ti) {
                const int n = g * 128 + wave * 32 + ti * 16 + c;
                #pragma unroll
                for (int ch = 0; ch < 4; ++ch) {
                    short8 vh;
                    #pragma unroll
                    for (int j = 0; j < 8; ++j) {
                        int k = ch * 32 + q * 8 + j;
                        vh[j] = (short)f2bf(W[(size_t)k * G3 + n]);
                    }
                    bfr[g][ti][ch] = vh;
                }
            }
    }
    const float bias_r0 = bh[dir * G3 +   0 + wave * 32 + c];
    const float bias_r1 = bh[dir * G3 +   0 + wave * 32 + 16 + c];
    const float bias_z0 = bh[dir * G3 + 128 + wave * 32 + c];
    const float bias_z1 = bh[dir * G3 + 128 + wave * 32 + 16 + c];
    const float bias_n0 = bh[dir * G3 + 256 + wave * 32 + c];
    const float bias_n1 = bh[dir * G3 + 256 + wave * 32 + 16 + c];

    // A-frags: rows 0-7 = h_hi, rows 8-15 = h_lo (replicated per row-half).
    short8 a[4];
    #pragma unroll
    for (int ch = 0; ch < 4; ++ch)
        #pragma unroll
        for (int j = 0; j < 8; ++j) a[ch][j] = 0;
    float ho0 = 0.f, ho1 = 0.f;      // h_old at this wave's two columns

    const int t0    = dir ? (TT - 1) : 0;
    const int gstep = dir ? -G3 : G3;   // xg pointer step (floats)
    const int ostep = dir ? -DD : DD;   // out pointer step (floats)

    const float* xp = XG + ((size_t)dir * MM + (size_t)b * TT + t0) * G3 + col0;
    float* op = Xout + ((size_t)b * TT + t0) * DD + dir * HH + col0;

    // depth-4 prefetch, in-place reload (no ring copies)
    XG6 x0 = load6(xp);
    XG6 x1 = load6(xp + gstep);
    XG6 x2 = load6(xp + 2 * gstep);
    XG6 x3 = load6(xp + 3 * gstep);

#define SUBSTEP(S, XV)                                                         \
    {                                                                          \
        f32x4 ar0 = {0.f,0.f,0.f,0.f}, az0 = {0.f,0.f,0.f,0.f},                \
              an0 = {0.f,0.f,0.f,0.f}, ar1 = {0.f,0.f,0.f,0.f},                \
              az1 = {0.f,0.f,0.f,0.f}, an1 = {0.f,0.f,0.f,0.f};                \
        _Pragma("unroll")                                                      \
        for (int ch = 0; ch < 4; ++ch) {                                       \
            ar0 = __builtin_amdgcn_mfma_f32_16x16x32_bf16(a[ch], bfr[0][0][ch], ar0, 0, 0, 0); \
            az0 = __builtin_amdgcn_mfma_f32_16x16x32_bf16(a[ch], bfr[1][0][ch], az0, 0, 0, 0); \
            an0 = __builtin_amdgcn_mfma_f32_16x16x32_bf16(a[ch], bfr[2][0][ch], an0, 0, 0, 0); \
            ar1 = __builtin_amdgcn_mfma_f32_16x16x32_bf16(a[ch], bfr[0][1][ch], ar1, 0, 0, 0); \
            az1 = __builtin_amdgcn_mfma_f32_16x16x32_bf16(a[ch], bfr[1][1][ch], az1, 0, 0, 0); \
            an1 = __builtin_amdgcn_mfma_f32_16x16x32_bf16(a[ch], bfr[2][1][ch], an1, 0, 0, 0); \
        }                                                                      \
        float hn0, hn1;                                                        \
        {                                                                      \
            float gr = permswap_add(ar0[0]);                                   \
            float gz = permswap_add(az0[0]);                                   \
            float gn = permswap_add(an0[0]);                                   \
            float pr = gr + XV.r[0] + bias_r0;                                 \
            float pz = gz + XV.z[0] + bias_z0;                                 \
            float pm = gn + bias_n0;                                           \
            float rg = fast_sigmoid(pr);                                       \
            float zg = fast_sigmoid(pz);                                       \
            float ng = fast_tanh(XV.n[0] + rg * pm);                           \
            hn0 = (1.f - zg) * ng + zg * ho0;                                  \
            ho0 = hn0;                                                         \
        }                                                                      \
        {                                                                      \
            float gr = permswap_add(ar1[0]);                                   \
            float gz = permswap_add(az1[0]);                                   \
            float gn = permswap_add(an1[0]);                                   \
            float pr = gr + XV.r[1] + bias_r1;                                 \
            float pz = gz + XV.z[1] + bias_z1;                                 \
            float pm = gn + bias_n1;                                           \
            float rg = fast_sigmoid(pr);                                       \
            float zg = fast_sigmoid(pz);                                       \
            float ng = fast_tanh(XV.n[1] + rg * pm);                           \
            hn1 = (1.f - zg) * ng + zg * ho1;                                  \
            ho1 = hn1;                                                         \
        }                                                                      \
        if (t + (S) + 4 < TT) { XV = load6(xp + ((S) + 4) * gstep); }          \
        const int pb = ((S) + 1) & 1;                                          \
        u16 hi0 = f2bf(hn0);                                                   \
        u16 hi1 = f2bf(hn1);                                                   \
        if (q == 0) {                                                          \
            op[(S) * ostep]      = hn0;                                        \
            op[(S) * ostep + 16] = hn1;                                        \
            hhi[pb][wave * 32 + c]      = hi0;                                 \
            hhi[pb][wave * 32 + 16 + c] = hi1;                                 \
        } else if (q == 1) {                                                   \
            hlo[pb][wave * 32 + c]      = f2bf(hn0 - bf2f(hi0));               \
            hlo[pb][wave * 32 + 16 + c] = f2bf(hn1 - bf2f(hi1));               \
        }                                                                      \
        asm volatile("s_waitcnt lgkmcnt(0)\n\ts_barrier" ::: "memory");        \
        if (t + (S) + 1 < TT) {                                                \
            const u16* hp = (c < 8) ? &hhi[pb][0] : &hlo[pb][0];               \
            _Pragma("unroll")                                                  \
            for (int ch = 0; ch < 4; ++ch)                                     \
                a[ch] = *(const short8*)(hp + ch * 32 + q * 8);                \
        }                                                                      \
    }

    for (int t = 0; t < TT; t += 4) {
        SUBSTEP(0, x0)
        SUBSTEP(1, x1)
        SUBSTEP(2, x2)
        SUBSTEP(3, x3)
        xp += 4 * gstep;
        op += 4 * ostep;
    }
#undef SUBSTEP
}

// ---------------- Launch ----------------
// ws: XG only = 2*65536*384*4 = 201.3 MB. Inter-layer activations ping-pong
// through d_out (each layer fully rewrites it before the next reads it).
extern "C" void kernel_launch(void* const* d_in, const int* in_sizes, int n_in,
                              void* d_out, int out_size, void* d_ws, size_t ws_size,
                              hipStream_t stream) {
    const float* x  = (const float*)d_in[0];   // [16,4096,256]
    const float* Wi = (const float*)d_in[1];   // [3,2,256,384]
    const float* Wh = (const float*)d_in[2];   // [3,2,128,384]
    const float* bh = (const float*)d_in[3];   // [3,2,384]
    float* out = (float*)d_out;                // [16,4096,256]

    float* XG = (float*)d_ws;                  // [2, 65536, 384] fp32

    for (int l = 0; l < 3; ++l) {
        const float* in  = (l == 0) ? x : out;
        const float* Wil = Wi + (size_t)l * 2 * DD * G3;
        const float* Whl = Wh + (size_t)l * 2 * HH * G3;
        const float* bhl = bh + (size_t)l * 2 * G3;

        gemm_in<<<dim3(6, MM / Bb), 256, 0, stream>>>(in, Wil, XG);
        gru_rec<<<32, 256, 0, stream>>>(XG, Whl, bhl, out);
    }
}

// Round 3
// 6461.414 us; speedup vs baseline: 1.3157x; 1.3157x over previous
//
#include <hip/hip_runtime.h>

// Problem constants
#define BB 16
#define TT 4096
#define DD 256     // DIM
#define HH 128     // hidden
#define G3 384     // 3*H
#define MM (BB*TT) // 65536 rows

typedef unsigned short u16;
typedef unsigned int u32;
typedef __attribute__((ext_vector_type(8))) short short8;  // 8 bf16 (4 VGPRs)
typedef __attribute__((ext_vector_type(4))) float f32x4;

__device__ __forceinline__ float bf2f(u16 u) {
    return __uint_as_float(((u32)u) << 16);
}
__device__ __forceinline__ u16 f2bf(float f) {
    u32 u = __float_as_uint(f);
    u32 lsb = (u >> 16) & 1u;
    u += 0x7fffu + lsb;      // RNE
    return (u16)(u >> 16);
}

// ---------------- Input-projection GEMM (fp32) ----------------
// XG[dir][m][0:384] = X[m][0:256] @ Wi[dir][0:256][0:384]
#define Bb 128
#define Bn 128
#define Bk 16

__global__ __launch_bounds__(256) void gemm_in(const float* __restrict__ X,
                                               const float* __restrict__ Wi,
                                               float* __restrict__ XG) {
    __shared__ __align__(16) float As[Bk][Bb + 4];
    __shared__ __align__(16) float Bs[Bk][Bn + 4];
    const int tid = threadIdx.x;
    const int m0  = blockIdx.y * Bb;
    const int nb  = blockIdx.x;
    const int n0  = nb * Bn;
    const int dir = (n0 >= G3) ? 1 : 0;
    const int nloc0 = n0 - dir * G3;
    const float* Wd = Wi + (size_t)dir * DD * G3;

    const int tx = tid & 15;
    const int ty = tid >> 4;
    float acc[8][8];
    #pragma unroll
    for (int i = 0; i < 8; ++i)
        #pragma unroll
        for (int j = 0; j < 8; ++j) acc[i][j] = 0.f;

    for (int k0 = 0; k0 < DD; k0 += Bk) {
        #pragma unroll
        for (int p = 0; p < 2; ++p) {
            int idx = tid + p * 256;
            int row = idx >> 2;
            int c4  = (idx & 3) * 4;
            float4 v = *(const float4*)(X + (size_t)(m0 + row) * DD + k0 + c4);
            As[c4 + 0][row] = v.x;
            As[c4 + 1][row] = v.y;
            As[c4 + 2][row] = v.z;
            As[c4 + 3][row] = v.w;
        }
        #pragma unroll
        for (int p = 0; p < 2; ++p) {
            int idx  = tid + p * 256;
            int krow = idx >> 5;
            int c4   = (idx & 31) * 4;
            float4 v = *(const float4*)(Wd + (size_t)(k0 + krow) * G3 + nloc0 + c4);
            *(float4*)(&Bs[krow][c4]) = v;
        }
        __syncthreads();
        #pragma unroll
        for (int k = 0; k < Bk; ++k) {
            float4 a0 = *(const float4*)(&As[k][ty * 8]);
            float4 a1 = *(const float4*)(&As[k][ty * 8 + 4]);
            float4 b0 = *(const float4*)(&Bs[k][tx * 8]);
            float4 b1 = *(const float4*)(&Bs[k][tx * 8 + 4]);
            float av[8] = {a0.x, a0.y, a0.z, a0.w, a1.x, a1.y, a1.z, a1.w};
            float bv[8] = {b0.x, b0.y, b0.z, b0.w, b1.x, b1.y, b1.z, b1.w};
            #pragma unroll
            for (int i = 0; i < 8; ++i)
                #pragma unroll
                for (int j = 0; j < 8; ++j) acc[i][j] += av[i] * bv[j];
        }
        __syncthreads();
    }
    #pragma unroll
    for (int i = 0; i < 8; ++i) {
        int m = m0 + ty * 8 + i;
        float* dst = XG + ((size_t)dir * MM + m) * G3 + nloc0 + tx * 8;
        *(float4*)dst       = make_float4(acc[i][0], acc[i][1], acc[i][2], acc[i][3]);
        *(float4*)(dst + 4) = make_float4(acc[i][4], acc[i][5], acc[i][6], acc[i][7]);
    }
}

// ---------------- MFMA recurrence, one WG per (dir,batch) ----------------
__device__ __forceinline__ float fast_sigmoid(float x) {
    float e = __expf(-x);
    return __builtin_amdgcn_rcpf(1.f + e);
}
__device__ __forceinline__ float fast_tanh(float x) {
    float e = __expf(2.f * x);
    return 1.f - 2.f * __builtin_amdgcn_rcpf(1.f + e);
}

// hi/lo recombine across the lane<32 / lane>=32 split on the VALU pipe
// (1 instr + add), instead of ds_bpermute (~130-cyc DS latency on the
// serial critical path). With A=B=g, a+b = g[lane] + g[lane^32].
__device__ __forceinline__ float permswap_add(float g) {
    float a = g;
    float b = g;
    asm("v_permlane32_swap_b32 %0, %1" : "+v"(a), "+v"(b));
    return a + b;
}

// One-instruction fp32->bf16 (any rounding is fine: lo captures the residual).
// dst.lo16 = bf16(f); take low 16 bits.
__device__ __forceinline__ u32 cvt_bf16(float f) {
    u32 pk;
    asm("v_cvt_pk_bf16_f32 %0, %1, %2" : "=v"(pk) : "v"(f), "v"(f));
    return pk;
}

struct XG3 { float r, z, n; };
__device__ __forceinline__ XG3 load3(const float* p) {
    XG3 v;
    v.r = p[0];
    v.z = p[128];
    v.n = p[256];
    return v;
}

// grid = 32 (dir,batch); block = 512 (8 waves, 2/SIMD). Wave w owns h-cols
// [16w,16w+16); 3 gate tiles = 12 MFMAs/wave/step (24/SIMD = floor).
//
// ROUND-2 BUG FIX: the in-place xg reload must happen AFTER the gates
// consume XV. We snapshot XV into locals at the top of the substep, THEN
// reload XV (prefetch t+4) — the snapshot is pure SSA renaming (no movs),
// the load issues before the MFMA block and stays in flight across the
// barrier; its vmcnt wait lands 4 substeps later.
//
// VALU diet vs round 0 (measured 520+ cyc/step of VALU issue):
//  - v_cvt_pk_bf16_f32 for the hi/lo bf16 split (~6 instrs vs ~28)
//  - 4x unroll makes the LDS ping-pong index compile-time -> ds addressing
//    folds into offset immediates
//  - depth-2 MFMA chains (latency insurance), scalar add at the end
// Row-split hi/lo trick unchanged: A rows 0-7 = h_hi, rows 8-15 = h_lo;
// permswap_add recombines -> ~fp32 precision.
__global__ __launch_bounds__(512, 1) void gru_rec(const float* __restrict__ XG,
                                                  const float* __restrict__ Wh,
                                                  const float* __restrict__ bh,
                                                  float* __restrict__ Xout) {
    const int wg   = blockIdx.x;     // 0..31
    const int dir  = wg & 1;
    const int b    = wg >> 1;
    const int tid  = threadIdx.x;
    const int lane = tid & 63;
    const int wave = tid >> 6;       // 0..7
    const int q    = lane >> 4;      // 0..3
    const int c    = lane & 15;
    const int hcol = wave * 16 + c;  // 0..127

    __shared__ __align__(16) u16 hhi[2][HH];   // ping-pong, bf16 hi
    __shared__ __align__(16) u16 hlo[2][HH];   // bf16 lo (residual)

    // ---- B-frag preload (Wh), plain bf16 ----
    // B layout (16x16x32): n = lane&15, k = (lane>>4)*8 + j
    short8 bfr[3][4];
    {
        const float* W = Wh + (size_t)dir * HH * G3;
        #pragma unroll
        for (int g = 0; g < 3; ++g) {
            const int n = g * 128 + hcol;
            #pragma unroll
            for (int ch = 0; ch < 4; ++ch) {
                short8 vh;
                #pragma unroll
                for (int j = 0; j < 8; ++j) {
                    int k = ch * 32 + q * 8 + j;
                    vh[j] = (short)f2bf(W[(size_t)k * G3 + n]);
                }
                bfr[g][ch] = vh;
            }
        }
    }
    float bias[3];
    #pragma unroll
    for (int g = 0; g < 3; ++g) bias[g] = bh[dir * G3 + g * 128 + hcol];

    // A-frags: rows 0-7 = h_hi, rows 8-15 = h_lo. Lane's row m = c; lanes
    // c<8 load from hhi, c>=8 from hlo. Zero at t=0.
    short8 a[4];
    #pragma unroll
    for (int ch = 0; ch < 4; ++ch)
        #pragma unroll
        for (int j = 0; j < 8; ++j) a[ch][j] = 0;
    float ho = 0.f;                  // h_old at this wave's column (fp32)

    const int t0    = dir ? (TT - 1) : 0;
    const int gstep = dir ? -G3 : G3;   // xg pointer step (floats)
    const int ostep = dir ? -DD : DD;   // out pointer step (floats)

    const float* xp = XG + ((size_t)dir * MM + (size_t)b * TT + t0) * G3 + hcol;
    float* op = Xout + ((size_t)b * TT + t0) * DD + dir * HH + hcol;

    // per-lane LDS bases (ping-pong + chunk become compile-time offsets)
    const u16* hrd = ((c < 8) ? &hhi[0][0] : &hlo[0][0]) + q * 8;
    u16* hw_hi = &hhi[0][hcol];
    u16* hw_lo = &hlo[0][hcol];

    // depth-4 prefetch, in-place reload (no ring copies)
    XG3 x0 = load3(xp);
    XG3 x1 = load3(xp + gstep);
    XG3 x2 = load3(xp + 2 * gstep);
    XG3 x3 = load3(xp + 3 * gstep);
    const float* xpf = xp + 4 * gstep;   // prefetch base (advances 2*gstep twice/iter)

#define SUBSTEP(S, XV, PK)                                                     \
    {                                                                          \
        /* snapshot current xg, then reload XV in place (prefetch t+S+4). */   \
        /* Snapshot = SSA rename (free); gates below read the snapshot. */     \
        float xr = XV.r, xz = XV.z, xn = XV.n;                                 \
        if (t + (S) + 4 < TT) { XV = load3(xpf + (PK) * gstep); }              \
        /* 12 MFMAs: depth-2 chains, 2 accumulators per gate */                \
        f32x4 r0 = {0.f,0.f,0.f,0.f}, r1 = {0.f,0.f,0.f,0.f};                  \
        f32x4 z0 = {0.f,0.f,0.f,0.f}, z1 = {0.f,0.f,0.f,0.f};                  \
        f32x4 n0 = {0.f,0.f,0.f,0.f}, n1 = {0.f,0.f,0.f,0.f};                  \
        r0 = __builtin_amdgcn_mfma_f32_16x16x32_bf16(a[0], bfr[0][0], r0, 0, 0, 0); \
        z0 = __builtin_amdgcn_mfma_f32_16x16x32_bf16(a[0], bfr[1][0], z0, 0, 0, 0); \
        n0 = __builtin_amdgcn_mfma_f32_16x16x32_bf16(a[0], bfr[2][0], n0, 0, 0, 0); \
        r1 = __builtin_amdgcn_mfma_f32_16x16x32_bf16(a[2], bfr[0][2], r1, 0, 0, 0); \
        z1 = __builtin_amdgcn_mfma_f32_16x16x32_bf16(a[2], bfr[1][2], z1, 0, 0, 0); \
        n1 = __builtin_amdgcn_mfma_f32_16x16x32_bf16(a[2], bfr[2][2], n1, 0, 0, 0); \
        r0 = __builtin_amdgcn_mfma_f32_16x16x32_bf16(a[1], bfr[0][1], r0, 0, 0, 0); \
        z0 = __builtin_amdgcn_mfma_f32_16x16x32_bf16(a[1], bfr[1][1], z0, 0, 0, 0); \
        n0 = __builtin_amdgcn_mfma_f32_16x16x32_bf16(a[1], bfr[2][1], n0, 0, 0, 0); \
        r1 = __builtin_amdgcn_mfma_f32_16x16x32_bf16(a[3], bfr[0][3], r1, 0, 0, 0); \
        z1 = __builtin_amdgcn_mfma_f32_16x16x32_bf16(a[3], bfr[1][3], z1, 0, 0, 0); \
        n1 = __builtin_amdgcn_mfma_f32_16x16x32_bf16(a[3], bfr[2][3], n1, 0, 0, 0); \
        float gr = permswap_add(r0[0] + r1[0]);                                \
        float gz = permswap_add(z0[0] + z1[0]);                                \
        float gn = permswap_add(n0[0] + n1[0]);                                \
        float pr = gr + xr + bias[0];                                          \
        float pz = gz + xz + bias[1];                                          \
        float pm = gn + bias[2];                                               \
        float rg = fast_sigmoid(pr);                                           \
        float zg = fast_sigmoid(pz);                                           \
        float ng = fast_tanh(xn + rg * pm);                                    \
        float hn = (1.f - zg) * ng + zg * ho;                                  \
        ho = hn;                                                               \
        /* hi/lo split: 1 cvt + shift + sub + 1 cvt */                         \
        u32 pk_hi = cvt_bf16(hn);                                              \
        float lo_f = hn - __uint_as_float(pk_hi << 16);                        \
        u32 pk_lo = cvt_bf16(lo_f);                                            \
        const int pb = ((S) + 1) & 1;                                          \
        if (q == 0) {                                                          \
            op[(S) * ostep] = hn;                                              \
            hw_hi[pb * HH]  = (u16)pk_hi;                                      \
        } else if (q == 1) {                                                   \
            hw_lo[pb * HH]  = (u16)pk_lo;                                      \
        }                                                                      \
        asm volatile("s_waitcnt lgkmcnt(0)\n\ts_barrier" ::: "memory");        \
        if (t + (S) + 1 < TT) {                                                \
            a[0] = *(const short8*)(hrd + pb * HH + 0);                        \
            a[1] = *(const short8*)(hrd + pb * HH + 32);                       \
            a[2] = *(const short8*)(hrd + pb * HH + 64);                       \
            a[3] = *(const short8*)(hrd + pb * HH + 96);                       \
        }                                                                      \
    }

    for (int t = 0; t < TT; t += 4) {
        SUBSTEP(0, x0, 0)
        SUBSTEP(1, x1, 1)
        xpf += 2 * gstep;
        SUBSTEP(2, x2, 0)
        SUBSTEP(3, x3, 1)
        xpf += 2 * gstep;
        op += 4 * ostep;
    }
#undef SUBSTEP
}

// ---------------- Launch ----------------
// ws: XG only = 2*65536*384*4 = 201.3 MB. Inter-layer activations ping-pong
// through d_out (each layer fully rewrites it before the next reads it).
extern "C" void kernel_launch(void* const* d_in, const int* in_sizes, int n_in,
                              void* d_out, int out_size, void* d_ws, size_t ws_size,
                              hipStream_t stream) {
    const float* x  = (const float*)d_in[0];   // [16,4096,256]
    const float* Wi = (const float*)d_in[1];   // [3,2,256,384]
    const float* Wh = (const float*)d_in[2];   // [3,2,128,384]
    const float* bh = (const float*)d_in[3];   // [3,2,384]
    float* out = (float*)d_out;                // [16,4096,256]

    float* XG = (float*)d_ws;                  // [2, 65536, 384] fp32

    for (int l = 0; l < 3; ++l) {
        const float* in  = (l == 0) ? x : out;
        const float* Wil = Wi + (size_t)l * 2 * DD * G3;
        const float* Whl = Wh + (size_t)l * 2 * HH * G3;
        const float* bhl = bh + (size_t)l * 2 * G3;

        gemm_in<<<dim3(6, MM / Bb), 256, 0, stream>>>(in, Wil, XG);
        gru_rec<<<32, 512, 0, stream>>>(XG, Whl, bhl, out);
    }
}

// Round 7
// 6244.502 us; speedup vs baseline: 1.3614x; 1.0347x over previous
//
#include <hip/hip_runtime.h>

// Problem constants
#define BB 16
#define TT 4096
#define DD 256     // DIM
#define HH 128     // hidden
#define G3 384     // 3*H
#define MM (BB*TT) // 65536 rows

typedef unsigned short u16;
typedef unsigned int u32;
typedef __attribute__((ext_vector_type(8))) short short8;  // 8 bf16 (4 VGPRs)
typedef __attribute__((ext_vector_type(4))) float f32x4;
typedef __attribute__((ext_vector_type(2))) unsigned int u32x2;

__device__ __forceinline__ float bf2f(u16 u) {
    return __uint_as_float(((u32)u) << 16);
}
__device__ __forceinline__ u16 f2bf(float f) {
    u32 u = __float_as_uint(f);
    u32 lsb = (u >> 16) & 1u;
    u += 0x7fffu + lsb;      // RNE
    return (u16)(u >> 16);
}

// ---------------- Input-projection GEMM (fp32) ----------------
// XG[dir][m][0:384] = X[m][0:256] @ Wi[dir][0:256][0:384]
#define Bb 128
#define Bn 128
#define Bk 16

__global__ __launch_bounds__(256) void gemm_in(const float* __restrict__ X,
                                               const float* __restrict__ Wi,
                                               float* __restrict__ XG) {
    __shared__ __align__(16) float As[Bk][Bb + 4];
    __shared__ __align__(16) float Bs[Bk][Bn + 4];
    const int tid = threadIdx.x;
    const int m0  = blockIdx.y * Bb;
    const int nb  = blockIdx.x;
    const int n0  = nb * Bn;
    const int dir = (n0 >= G3) ? 1 : 0;
    const int nloc0 = n0 - dir * G3;
    const float* Wd = Wi + (size_t)dir * DD * G3;

    const int tx = tid & 15;
    const int ty = tid >> 4;
    float acc[8][8];
    #pragma unroll
    for (int i = 0; i < 8; ++i)
        #pragma unroll
        for (int j = 0; j < 8; ++j) acc[i][j] = 0.f;

    for (int k0 = 0; k0 < DD; k0 += Bk) {
        #pragma unroll
        for (int p = 0; p < 2; ++p) {
            int idx = tid + p * 256;
            int row = idx >> 2;
            int c4  = (idx & 3) * 4;
            float4 v = *(const float4*)(X + (size_t)(m0 + row) * DD + k0 + c4);
            As[c4 + 0][row] = v.x;
            As[c4 + 1][row] = v.y;
            As[c4 + 2][row] = v.z;
            As[c4 + 3][row] = v.w;
        }
        #pragma unroll
        for (int p = 0; p < 2; ++p) {
            int idx  = tid + p * 256;
            int krow = idx >> 5;
            int c4   = (idx & 31) * 4;
            float4 v = *(const float4*)(Wd + (size_t)(k0 + krow) * G3 + nloc0 + c4);
            *(float4*)(&Bs[krow][c4]) = v;
        }
        __syncthreads();
        #pragma unroll
        for (int k = 0; k < Bk; ++k) {
            float4 a0 = *(const float4*)(&As[k][ty * 8]);
            float4 a1 = *(const float4*)(&As[k][ty * 8 + 4]);
            float4 b0 = *(const float4*)(&Bs[k][tx * 8]);
            float4 b1 = *(const float4*)(&Bs[k][tx * 8 + 4]);
            float av[8] = {a0.x, a0.y, a0.z, a0.w, a1.x, a1.y, a1.z, a1.w};
            float bv[8] = {b0.x, b0.y, b0.z, b0.w, b1.x, b1.y, b1.z, b1.w};
            #pragma unroll
            for (int i = 0; i < 8; ++i)
                #pragma unroll
                for (int j = 0; j < 8; ++j) acc[i][j] += av[i] * bv[j];
        }
        __syncthreads();
    }
    #pragma unroll
    for (int i = 0; i < 8; ++i) {
        int m = m0 + ty * 8 + i;
        float* dst = XG + ((size_t)dir * MM + m) * G3 + nloc0 + tx * 8;
        *(float4*)dst       = make_float4(acc[i][0], acc[i][1], acc[i][2], acc[i][3]);
        *(float4*)(dst + 4) = make_float4(acc[i][4], acc[i][5], acc[i][6], acc[i][7]);
    }
}

// ---------------- MFMA recurrence, one WG per (dir,batch) ----------------
__device__ __forceinline__ float fast_sigmoid(float x) {
    float e = __expf(-x);
    return __builtin_amdgcn_rcpf(1.f + e);
}
__device__ __forceinline__ float fast_tanh(float x) {
    float e = __expf(2.f * x);
    return 1.f - 2.f * __builtin_amdgcn_rcpf(1.f + e);
}

// hi/lo recombine across the lane<32 / lane>=32 split on the VALU pipe.
// v_permlane32_swap_b32 with vdst=vsrc=g:
//   result0 = {g[l+32] (l<32) | g[l] (l>=32)}
//   result1 = {g[l]    (l<32) | g[l-32] (l>=32)}
// -> r0 + r1 = g[lane] + g[lane^32] in every lane.
// Use the INTRINSIC (two-result, properly modeled def/use) instead of
// inline asm: round 4's tied-asm form let the allocator coalesce both
// inputs into one register (v_permlane32_swap v5,v5 -> recurrent term
// dropped, absmax 0.44); the intrinsic makes that impossible.
__device__ __forceinline__ float permswap_add(float g) {
    u32 gu = __float_as_uint(g);
    u32x2 r = __builtin_amdgcn_permlane32_swap(gu, gu, false, false);
    return __uint_as_float(r[0]) + __uint_as_float(r[1]);
}

// One-instruction fp32->bf16 (any rounding fine: lo captures the residual).
__device__ __forceinline__ u32 cvt_bf16(float f) {
    u32 pk;
    asm("v_cvt_pk_bf16_f32 %0, %1, %2" : "=v"(pk) : "v"(f), "v"(f));
    return pk;
}

struct XG3 { float r, z, n; };
__device__ __forceinline__ XG3 load3(const float* p) {
    XG3 v;
    v.r = p[0];
    v.z = p[128];
    v.n = p[256];
    return v;
}

// grid = 32 (dir,batch); block = 512 (8 waves, 2/SIMD). Wave w owns h-cols
// [16w,16w+16); 3 gate tiles = 12 MFMAs/wave/step (24/SIMD, ~384 cyc floor).
//
// VALU diet (round 3 measured VALU issue 536 cyc/SIMD/step > MFMA 384):
//  1. Persistent accumulators, NO zero-init: per substep only element 0 is
//     written with 0.5*(xg+bias) (halved because permswap_add sums the
//     hi-quad and lo-quad lanes, each carrying the same C-init). Elements
//     1-3 hold stale garbage that is never read and stays finite (~1e4
//     after 4096 steps; |h|<1). Kills 24 v_mov + 9 adds per substep.
//  2. LDS: 64B pad between hhi and hlo (single hbuf array so placement is
//     guaranteed). hlo base moves from bank 0 to bank 16 -> A-frag
//     ds_read_b128 has one address per bank (round 3 measured 1.68e7
//     conflict cycles from the 2-address aliasing).
// Row-split hi/lo trick unchanged: A rows 0-7 = h_hi, rows 8-15 = h_lo;
// permswap_add recombines -> ~fp32 precision.
#define HLO_OFF (2 * HH + 32)   // u16 elements; hlo base = byte 576 = bank 16

__global__ __launch_bounds__(512, 1) void gru_rec(const float* __restrict__ XG,
                                                  const float* __restrict__ Wh,
                                                  const float* __restrict__ bh,
                                                  float* __restrict__ Xout) {
    const int wg   = blockIdx.x;     // 0..31
    const int dir  = wg & 1;
    const int b    = wg >> 1;
    const int tid  = threadIdx.x;
    const int lane = tid & 63;
    const int wave = tid >> 6;       // 0..7
    const int q    = lane >> 4;      // 0..3
    const int c    = lane & 15;
    const int hcol = wave * 16 + c;  // 0..127

    // [hhi ping|pong (2*HH)] [pad 32] [hlo ping|pong (2*HH)]
    __shared__ __align__(16) u16 hbuf[HLO_OFF + 2 * HH];

    // ---- B-frag preload (Wh), plain bf16 ----
    // B layout (16x16x32): n = lane&15, k = (lane>>4)*8 + j
    short8 bfr[3][4];
    {
        const float* W = Wh + (size_t)dir * HH * G3;
        #pragma unroll
        for (int g = 0; g < 3; ++g) {
            const int n = g * 128 + hcol;
            #pragma unroll
            for (int ch = 0; ch < 4; ++ch) {
                short8 vh;
                #pragma unroll
                for (int j = 0; j < 8; ++j) {
                    int k = ch * 32 + q * 8 + j;
                    vh[j] = (short)f2bf(W[(size_t)k * G3 + n]);
                }
                bfr[g][ch] = vh;
            }
        }
    }
    // halved biases (C-init is added twice via the hi/lo lane sum)
    float hb[3];
    #pragma unroll
    for (int g = 0; g < 3; ++g) hb[g] = 0.5f * bh[dir * G3 + g * 128 + hcol];

    // A-frags: rows 0-7 = h_hi, rows 8-15 = h_lo. Zero at t=0.
    short8 a[4];
    #pragma unroll
    for (int ch = 0; ch < 4; ++ch)
        #pragma unroll
        for (int j = 0; j < 8; ++j) a[ch][j] = 0;
    float ho = 0.f;                  // h_old at this wave's column (fp32)

    // persistent accumulators (elements 1-3 never read after init)
    f32x4 accR = {0.f, 0.f, 0.f, 0.f};
    f32x4 accZ = {0.f, 0.f, 0.f, 0.f};
    f32x4 accN = {0.f, 0.f, 0.f, 0.f};

    const int t0    = dir ? (TT - 1) : 0;
    const int gstep = dir ? -G3 : G3;   // xg pointer step (floats)
    const int ostep = dir ? -DD : DD;   // out pointer step (floats)

    const float* xp = XG + ((size_t)dir * MM + (size_t)b * TT + t0) * G3 + hcol;
    float* op = Xout + ((size_t)b * TT + t0) * DD + dir * HH + hcol;

    // per-lane LDS bases (ping-pong + chunk become compile-time offsets)
    const u16* hrd = hbuf + ((c < 8) ? 0 : HLO_OFF) + q * 8;
    u16* hw_hi = hbuf + hcol;
    u16* hw_lo = hbuf + HLO_OFF + hcol;

    // depth-4 prefetch, in-place reload (no ring copies)
    XG3 x0 = load3(xp);
    XG3 x1 = load3(xp + gstep);
    XG3 x2 = load3(xp + 2 * gstep);
    XG3 x3 = load3(xp + 3 * gstep);
    const float* xpf = xp + 4 * gstep;   // prefetch base (advances 2*gstep twice/iter)

#define SUBSTEP(S, XV, PK)                                                     \
    {                                                                          \
        /* snapshot current xg, then reload XV in place (prefetch t+S+4) */    \
        float xr = XV.r, xz = XV.z, xn = XV.n;                                 \
        if (t + (S) + 4 < TT) { XV = load3(xpf + (PK) * gstep); }              \
        /* C-init: elem0 = 0.5*(xg+bias); permswap doubles it back */          \
        accR[0] = __builtin_fmaf(0.5f, xr, hb[0]);                             \
        accZ[0] = __builtin_fmaf(0.5f, xz, hb[1]);                             \
        accN[0] = hb[2];                                                       \
        /* 12 MFMAs: 3 independent depth-4 chains */                           \
        _Pragma("unroll")                                                      \
        for (int ch = 0; ch < 4; ++ch) {                                       \
            accR = __builtin_amdgcn_mfma_f32_16x16x32_bf16(a[ch], bfr[0][ch], accR, 0, 0, 0); \
            accZ = __builtin_amdgcn_mfma_f32_16x16x32_bf16(a[ch], bfr[1][ch], accZ, 0, 0, 0); \
            accN = __builtin_amdgcn_mfma_f32_16x16x32_bf16(a[ch], bfr[2][ch], accN, 0, 0, 0); \
        }                                                                      \
        float pr = permswap_add(accR[0]);                                      \
        float pz = permswap_add(accZ[0]);                                      \
        float pm = permswap_add(accN[0]);                                      \
        float rg = fast_sigmoid(pr);                                           \
        float zg = fast_sigmoid(pz);                                           \
        float ng = fast_tanh(xn + rg * pm);                                    \
        float hn = (1.f - zg) * ng + zg * ho;                                  \
        ho = hn;                                                               \
        /* hi/lo split: 1 cvt + shift + sub + 1 cvt */                         \
        u32 pk_hi = cvt_bf16(hn);                                              \
        float lo_f = hn - __uint_as_float(pk_hi << 16);                        \
        u32 pk_lo = cvt_bf16(lo_f);                                            \
        const int pb = ((S) + 1) & 1;                                          \
        if (q == 0) {                                                          \
            op[(S) * ostep] = hn;                                              \
            hw_hi[pb * HH]  = (u16)pk_hi;                                      \
        } else if (q == 1) {                                                   \
            hw_lo[pb * HH]  = (u16)pk_lo;                                      \
        }                                                                      \
        asm volatile("s_waitcnt lgkmcnt(0)\n\ts_barrier" ::: "memory");        \
        if (t + (S) + 1 < TT) {                                                \
            a[0] = *(const short8*)(hrd + pb * HH + 0);                        \
            a[1] = *(const short8*)(hrd + pb * HH + 32);                       \
            a[2] = *(const short8*)(hrd + pb * HH + 64);                       \
            a[3] = *(const short8*)(hrd + pb * HH + 96);                       \
        }                                                                      \
    }

    for (int t = 0; t < TT; t += 4) {
        SUBSTEP(0, x0, 0)
        SUBSTEP(1, x1, 1)
        xpf += 2 * gstep;
        SUBSTEP(2, x2, 0)
        SUBSTEP(3, x3, 1)
        xpf += 2 * gstep;
        op += 4 * ostep;
    }
#undef SUBSTEP
}

// ---------------- Launch ----------------
// ws: XG only = 2*65536*384*4 = 201.3 MB. Inter-layer activations ping-pong
// through d_out (each layer fully rewrites it before the next reads it).
extern "C" void kernel_launch(void* const* d_in, const int* in_sizes, int n_in,
                              void* d_out, int out_size, void* d_ws, size_t ws_size,
                              hipStream_t stream) {
    const float* x  = (const float*)d_in[0];   // [16,4096,256]
    const float* Wi = (const float*)d_in[1];   // [3,2,256,384]
    const float* Wh = (const float*)d_in[2];   // [3,2,128,384]
    const float* bh = (const float*)d_in[3];   // [3,2,384]
    float* out = (float*)d_out;                // [16,4096,256]

    float* XG = (float*)d_ws;                  // [2, 65536, 384] fp32

    for (int l = 0; l < 3; ++l) {
        const float* in  = (l == 0) ? x : out;
        const float* Wil = Wi + (size_t)l * 2 * DD * G3;
        const float* Whl = Wh + (size_t)l * 2 * HH * G3;
        const float* bhl = bh + (size_t)l * 2 * G3;

        gemm_in<<<dim3(6, MM / Bb), 256, 0, stream>>>(in, Wil, XG);
        gru_rec<<<32, 512, 0, stream>>>(XG, Whl, bhl, out);
    }
}

// Round 8
// 5667.035 us; speedup vs baseline: 1.5001x; 1.1019x over previous
//
#include <hip/hip_runtime.h>

// Problem constants
#define BB 16
#define TT 4096
#define DD 256     // DIM
#define HH 128     // hidden
#define G3 384     // 3*H
#define MM (BB*TT) // 65536 rows

typedef unsigned short u16;
typedef unsigned int u32;
typedef __attribute__((ext_vector_type(8))) short short8;  // 8 bf16 (4 VGPRs)
typedef __attribute__((ext_vector_type(4))) float f32x4;
typedef __attribute__((ext_vector_type(2))) unsigned int u32x2;
typedef __attribute__((ext_vector_type(4))) unsigned int u32x4;

__device__ __forceinline__ float bf2f(u16 u) {
    return __uint_as_float(((u32)u) << 16);
}
__device__ __forceinline__ u16 f2bf(float f) {
    u32 u = __float_as_uint(f);
    u32 lsb = (u >> 16) & 1u;
    u += 0x7fffu + lsb;      // RNE
    return (u16)(u >> 16);
}

// v_cvt_pk_bf16_f32: packs bf16(x) in low16, bf16(y) in high16.
__device__ __forceinline__ u32 cvt_pk2(float x, float y) {
    u32 pk;
    asm("v_cvt_pk_bf16_f32 %0, %1, %2" : "=v"(pk) : "v"(x), "v"(y));
    return pk;
}
// One-float variant (low 16 bits valid).
__device__ __forceinline__ u32 cvt_bf16(float f) {
    u32 pk;
    asm("v_cvt_pk_bf16_f32 %0, %1, %2" : "=v"(pk) : "v"(f), "v"(f));
    return pk;
}
// Convert 2 fp32 -> packed bf16 hi-pair + packed bf16 residual(lo)-pair.
__device__ __forceinline__ void cvt2_hilo(float x, float y, u32& hi, u32& lo) {
    u32 h = cvt_pk2(x, y);
    float rx = x - __uint_as_float(h << 16);
    float ry = y - __uint_as_float(h & 0xffff0000u);
    hi = h;
    lo = cvt_pk2(rx, ry);
}

// ---------------- Input-projection GEMM: 3-term bf16 MFMA ----------------
// XG[dir][m][0:384] = X[m][0:256] @ Wi[dir][0:256][0:384], fp32 in/out.
// Split A = Ahi + Alo, B = Bhi + Blo (bf16 each); C = Ahi*Bhi + Ahi*Blo +
// Alo*Bhi (+ Alo*Blo dropped: ~2^-18 relative -> output error ~1e-5,
// negligible vs the kernel's 3.9e-3 absmax). fp32 MFMA accumulate.
// Fragment conventions copied from the VERIFIED gru_rec kernel:
//   A: m = lane&15, k = (lane>>4)*8 + j   (8 bf16 per lane, b128)
//   B: n = lane&15, k = (lane>>4)*8 + j
//   C: col = lane&15, row = (lane>>4)*4 + reg
#define GBM 128
#define GBN 128
#define GBK 32
#define APAD 40   // u16 row stride (80 B, 16B-aligned; breaks pow2 bank alias)

__global__ __launch_bounds__(256, 2) void gemm_in(const float* __restrict__ X,
                                                  const float* __restrict__ Wi,
                                                  float* __restrict__ XG) {
    __shared__ __align__(16) u16 Ahi[GBM][APAD];
    __shared__ __align__(16) u16 Alo[GBM][APAD];
    __shared__ __align__(16) u16 Bhi[GBN][APAD];   // transposed: [n][k]
    __shared__ __align__(16) u16 Blo[GBN][APAD];

    const int tid = threadIdx.x;
    const int m0  = blockIdx.y * GBM;
    const int gc0 = blockIdx.x * GBN;          // 0..767 in steps of 128
    const int dir = (gc0 >= G3) ? 1 : 0;
    const int n0  = gc0 - dir * G3;            // 0,128,256
    const float* Wd = Wi + (size_t)dir * DD * G3;

    const int lane = tid & 63;
    const int wv   = tid >> 6;    // 0..3
    const int wr   = wv >> 1;     // wave-row: owns rows [wr*64, wr*64+64)
    const int wc   = wv & 1;      // wave-col: owns cols [wc*64, wc*64+64)
    const int q    = lane >> 4;
    const int c    = lane & 15;

    f32x4 acc[4][4];
    #pragma unroll
    for (int i = 0; i < 4; ++i)
        #pragma unroll
        for (int j = 0; j < 4; ++j) acc[i][j] = (f32x4){0.f, 0.f, 0.f, 0.f};

    // B staging mapping: thread -> (n, k-half); strided-k loads are
    // wave-coalesced along n (64 consecutive floats per k-row).
    const int bn  = tid & 127;
    const int bkh = (tid >> 7) * 16;

    for (int k0 = 0; k0 < DD; k0 += GBK) {
        // ---- stage A: 128x32 fp32 -> bf16 hi/lo ----
        #pragma unroll
        for (int p = 0; p < 4; ++p) {
            int idx = tid + p * 256;           // 0..1023
            int row = idx >> 3;                // 0..127
            int k4  = (idx & 7) * 4;           // 0,4,...,28
            float4 v = *(const float4*)(X + (size_t)(m0 + row) * DD + k0 + k4);
            u32 h01, l01, h23, l23;
            cvt2_hilo(v.x, v.y, h01, l01);
            cvt2_hilo(v.z, v.w, h23, l23);
            *(u32x2*)(&Ahi[row][k4]) = (u32x2){h01, h23};
            *(u32x2*)(&Alo[row][k4]) = (u32x2){l01, l23};
        }
        // ---- stage B: 32x128 fp32 -> bf16 hi/lo, transposed [n][k] ----
        {
            float bv[16];
            #pragma unroll
            for (int j = 0; j < 16; ++j)
                bv[j] = Wd[(size_t)(k0 + bkh + j) * G3 + n0 + bn];
            u32 h[8], l[8];
            #pragma unroll
            for (int j = 0; j < 8; ++j)
                cvt2_hilo(bv[2 * j], bv[2 * j + 1], h[j], l[j]);
            *(u32x4*)(&Bhi[bn][bkh + 0]) = (u32x4){h[0], h[1], h[2], h[3]};
            *(u32x4*)(&Bhi[bn][bkh + 8]) = (u32x4){h[4], h[5], h[6], h[7]};
            *(u32x4*)(&Blo[bn][bkh + 0]) = (u32x4){l[0], l[1], l[2], l[3]};
            *(u32x4*)(&Blo[bn][bkh + 8]) = (u32x4){l[4], l[5], l[6], l[7]};
        }
        __syncthreads();
        // ---- compute: 16 frags x 3 terms = 48 MFMAs per wave ----
        short8 afh[4], afl[4], bfh[4], bfl[4];
        #pragma unroll
        for (int i = 0; i < 4; ++i) {
            afh[i] = *(const short8*)(&Ahi[wr * 64 + i * 16 + c][q * 8]);
            afl[i] = *(const short8*)(&Alo[wr * 64 + i * 16 + c][q * 8]);
            bfh[i] = *(const short8*)(&Bhi[wc * 64 + i * 16 + c][q * 8]);
            bfl[i] = *(const short8*)(&Blo[wc * 64 + i * 16 + c][q * 8]);
        }
        #pragma unroll
        for (int i = 0; i < 4; ++i)
            #pragma unroll
            for (int j = 0; j < 4; ++j) {
                acc[i][j] = __builtin_amdgcn_mfma_f32_16x16x32_bf16(afh[i], bfh[j], acc[i][j], 0, 0, 0);
                acc[i][j] = __builtin_amdgcn_mfma_f32_16x16x32_bf16(afh[i], bfl[j], acc[i][j], 0, 0, 0);
                acc[i][j] = __builtin_amdgcn_mfma_f32_16x16x32_bf16(afl[i], bfh[j], acc[i][j], 0, 0, 0);
            }
        __syncthreads();
    }
    // ---- epilogue: C[row = q*4+r][col = c] ----
    #pragma unroll
    for (int i = 0; i < 4; ++i) {
        #pragma unroll
        for (int j = 0; j < 4; ++j) {
            const int n = n0 + wc * 64 + j * 16 + c;
            #pragma unroll
            for (int r = 0; r < 4; ++r) {
                const int m = m0 + wr * 64 + i * 16 + q * 4 + r;
                XG[((size_t)dir * MM + m) * G3 + n] = acc[i][j][r];
            }
        }
    }
}

// ---------------- MFMA recurrence, one WG per (dir,batch) ----------------
// (byte-identical to the round-7 verified kernel)
__device__ __forceinline__ float fast_sigmoid(float x) {
    float e = __expf(-x);
    return __builtin_amdgcn_rcpf(1.f + e);
}
__device__ __forceinline__ float fast_tanh(float x) {
    float e = __expf(2.f * x);
    return 1.f - 2.f * __builtin_amdgcn_rcpf(1.f + e);
}

// hi/lo recombine across the lane<32 / lane>=32 split on the VALU pipe.
// v_permlane32_swap_b32 with vdst=vsrc=g:
//   result0 = {g[l+32] (l<32) | g[l] (l>=32)}
//   result1 = {g[l]    (l<32) | g[l-32] (l>=32)}
// -> r0 + r1 = g[lane] + g[lane^32] in every lane.
// Intrinsic (two-result, properly modeled def/use) — the round-4 tied-asm
// form let the allocator coalesce both inputs into one register.
__device__ __forceinline__ float permswap_add(float g) {
    u32 gu = __float_as_uint(g);
    u32x2 r = __builtin_amdgcn_permlane32_swap(gu, gu, false, false);
    return __uint_as_float(r[0]) + __uint_as_float(r[1]);
}

struct XG3 { float r, z, n; };
__device__ __forceinline__ XG3 load3(const float* p) {
    XG3 v;
    v.r = p[0];
    v.z = p[128];
    v.n = p[256];
    return v;
}

// grid = 32 (dir,batch); block = 512 (8 waves, 2/SIMD). Wave w owns h-cols
// [16w,16w+16); 3 gate tiles = 12 MFMAs/wave/step (24/SIMD, ~384 cyc floor).
//
//  1. Persistent accumulators, NO zero-init: per substep only element 0 is
//     written with 0.5*(xg+bias) (halved because permswap_add sums the
//     hi-quad and lo-quad lanes, each carrying the same C-init). Elements
//     1-3 hold stale garbage that is never read and stays finite.
//  2. LDS: 64B pad between hhi and hlo -> hlo base at bank 16 -> A-frag
//     ds_read_b128 has one address per bank (measured conflicts: 0).
// Row-split hi/lo trick: A rows 0-7 = h_hi, rows 8-15 = h_lo;
// permswap_add recombines -> ~fp32 precision.
#define HLO_OFF (2 * HH + 32)   // u16 elements; hlo base = byte 576 = bank 16

__global__ __launch_bounds__(512, 1) void gru_rec(const float* __restrict__ XG,
                                                  const float* __restrict__ Wh,
                                                  const float* __restrict__ bh,
                                                  float* __restrict__ Xout) {
    const int wg   = blockIdx.x;     // 0..31
    const int dir  = wg & 1;
    const int b    = wg >> 1;
    const int tid  = threadIdx.x;
    const int lane = tid & 63;
    const int wave = tid >> 6;       // 0..7
    const int q    = lane >> 4;      // 0..3
    const int c    = lane & 15;
    const int hcol = wave * 16 + c;  // 0..127

    // [hhi ping|pong (2*HH)] [pad 32] [hlo ping|pong (2*HH)]
    __shared__ __align__(16) u16 hbuf[HLO_OFF + 2 * HH];

    // ---- B-frag preload (Wh), plain bf16 ----
    // B layout (16x16x32): n = lane&15, k = (lane>>4)*8 + j
    short8 bfr[3][4];
    {
        const float* W = Wh + (size_t)dir * HH * G3;
        #pragma unroll
        for (int g = 0; g < 3; ++g) {
            const int n = g * 128 + hcol;
            #pragma unroll
            for (int ch = 0; ch < 4; ++ch) {
                short8 vh;
                #pragma unroll
                for (int j = 0; j < 8; ++j) {
                    int k = ch * 32 + q * 8 + j;
                    vh[j] = (short)f2bf(W[(size_t)k * G3 + n]);
                }
                bfr[g][ch] = vh;
            }
        }
    }
    // halved biases (C-init is added twice via the hi/lo lane sum)
    float hb[3];
    #pragma unroll
    for (int g = 0; g < 3; ++g) hb[g] = 0.5f * bh[dir * G3 + g * 128 + hcol];

    // A-frags: rows 0-7 = h_hi, rows 8-15 = h_lo. Zero at t=0.
    short8 a[4];
    #pragma unroll
    for (int ch = 0; ch < 4; ++ch)
        #pragma unroll
        for (int j = 0; j < 8; ++j) a[ch][j] = 0;
    float ho = 0.f;                  // h_old at this wave's column (fp32)

    // persistent accumulators (elements 1-3 never read after init)
    f32x4 accR = {0.f, 0.f, 0.f, 0.f};
    f32x4 accZ = {0.f, 0.f, 0.f, 0.f};
    f32x4 accN = {0.f, 0.f, 0.f, 0.f};

    const int t0    = dir ? (TT - 1) : 0;
    const int gstep = dir ? -G3 : G3;   // xg pointer step (floats)
    const int ostep = dir ? -DD : DD;   // out pointer step (floats)

    const float* xp = XG + ((size_t)dir * MM + (size_t)b * TT + t0) * G3 + hcol;
    float* op = Xout + ((size_t)b * TT + t0) * DD + dir * HH + hcol;

    // per-lane LDS bases (ping-pong + chunk become compile-time offsets)
    const u16* hrd = hbuf + ((c < 8) ? 0 : HLO_OFF) + q * 8;
    u16* hw_hi = hbuf + hcol;
    u16* hw_lo = hbuf + HLO_OFF + hcol;

    // depth-4 prefetch, in-place reload (no ring copies)
    XG3 x0 = load3(xp);
    XG3 x1 = load3(xp + gstep);
    XG3 x2 = load3(xp + 2 * gstep);
    XG3 x3 = load3(xp + 3 * gstep);
    const float* xpf = xp + 4 * gstep;   // prefetch base (advances 2*gstep twice/iter)

#define SUBSTEP(S, XV, PK)                                                     \
    {                                                                          \
        /* snapshot current xg, then reload XV in place (prefetch t+S+4) */    \
        float xr = XV.r, xz = XV.z, xn = XV.n;                                 \
        if (t + (S) + 4 < TT) { XV = load3(xpf + (PK) * gstep); }              \
        /* C-init: elem0 = 0.5*(xg+bias); permswap doubles it back */          \
        accR[0] = __builtin_fmaf(0.5f, xr, hb[0]);                             \
        accZ[0] = __builtin_fmaf(0.5f, xz, hb[1]);                             \
        accN[0] = hb[2];                                                       \
        /* 12 MFMAs: 3 independent depth-4 chains */                           \
        _Pragma("unroll")                                                      \
        for (int ch = 0; ch < 4; ++ch) {                                       \
            accR = __builtin_amdgcn_mfma_f32_16x16x32_bf16(a[ch], bfr[0][ch], accR, 0, 0, 0); \
            accZ = __builtin_amdgcn_mfma_f32_16x16x32_bf16(a[ch], bfr[1][ch], accZ, 0, 0, 0); \
            accN = __builtin_amdgcn_mfma_f32_16x16x32_bf16(a[ch], bfr[2][ch], accN, 0, 0, 0); \
        }                                                                      \
        float pr = permswap_add(accR[0]);                                      \
        float pz = permswap_add(accZ[0]);                                      \
        float pm = permswap_add(accN[0]);                                      \
        float rg = fast_sigmoid(pr);                                           \
        float zg = fast_sigmoid(pz);                                           \
        float ng = fast_tanh(xn + rg * pm);                                    \
        float hn = (1.f - zg) * ng + zg * ho;                                  \
        ho = hn;                                                               \
        /* hi/lo split: 1 cvt + shift + sub + 1 cvt */                         \
        u32 pk_hi = cvt_bf16(hn);                                              \
        float lo_f = hn - __uint_as_float(pk_hi << 16);                        \
        u32 pk_lo = cvt_bf16(lo_f);                                            \
        const int pb = ((S) + 1) & 1;                                          \
        if (q == 0) {                                                          \
            op[(S) * ostep] = hn;                                              \
            hw_hi[pb * HH]  = (u16)pk_hi;                                      \
        } else if (q == 1) {                                                   \
            hw_lo[pb * HH]  = (u16)pk_lo;                                      \
        }                                                                      \
        asm volatile("s_waitcnt lgkmcnt(0)\n\ts_barrier" ::: "memory");        \
        if (t + (S) + 1 < TT) {                                                \
            a[0] = *(const short8*)(hrd + pb * HH + 0);                        \
            a[1] = *(const short8*)(hrd + pb * HH + 32);                       \
            a[2] = *(const short8*)(hrd + pb * HH + 64);                       \
            a[3] = *(const short8*)(hrd + pb * HH + 96);                       \
        }                                                                      \
    }

    for (int t = 0; t < TT; t += 4) {
        SUBSTEP(0, x0, 0)
        SUBSTEP(1, x1, 1)
        xpf += 2 * gstep;
        SUBSTEP(2, x2, 0)
        SUBSTEP(3, x3, 1)
        xpf += 2 * gstep;
        op += 4 * ostep;
    }
#undef SUBSTEP
}

// ---------------- Launch ----------------
// ws: XG only = 2*65536*384*4 = 201.3 MB. Inter-layer activations ping-pong
// through d_out (each layer fully rewrites it before the next reads it).
extern "C" void kernel_launch(void* const* d_in, const int* in_sizes, int n_in,
                              void* d_out, int out_size, void* d_ws, size_t ws_size,
                              hipStream_t stream) {
    const float* x  = (const float*)d_in[0];   // [16,4096,256]
    const float* Wi = (const float*)d_in[1];   // [3,2,256,384]
    const float* Wh = (const float*)d_in[2];   // [3,2,128,384]
    const float* bh = (const float*)d_in[3];   // [3,2,384]
    float* out = (float*)d_out;                // [16,4096,256]

    float* XG = (float*)d_ws;                  // [2, 65536, 384] fp32

    for (int l = 0; l < 3; ++l) {
        const float* in  = (l == 0) ? x : out;
        const float* Wil = Wi + (size_t)l * 2 * DD * G3;
        const float* Whl = Wh + (size_t)l * 2 * HH * G3;
        const float* bhl = bh + (size_t)l * 2 * G3;

        gemm_in<<<dim3(6, MM / GBM), 256, 0, stream>>>(in, Wil, XG);
        gru_rec<<<32, 512, 0, stream>>>(XG, Whl, bhl, out);
    }
}